// Round 8
// baseline (3474.530 us; speedup 1.0000x reference)
//
#include <hip/hip_runtime.h>

// GrammarInference: encoder tanh-RNN (128 steps) + GRU decoder (63 steps) + per-step head.
// R7 counters: dec latency-bound on L2 capacity misses (FETCH 1.72GB, 46% miss of the
// weight stream; per-XCD working set ~3.6-4MB >= 4MB L2). R8 fix: hoist prog_proj back
// into registers (step-invariant; dec-v2 had dropped R2's hoist) -> -395MB traffic,
// -786KB/XCD working set (now ~2.8MB < 4MB), -12 loads/thread/step.
//
// B=2048 P=128 T=64 V=1000 NC=32 NO=16 E=300 H=256 GIN=856, out = [63,2048,16] f32.

typedef unsigned short ushort_t;
typedef short short8 __attribute__((ext_vector_type(8)));
typedef float f32x4_t __attribute__((ext_vector_type(4)));

__device__ __forceinline__ ushort_t f32_to_bf16_rne(float f){
    unsigned int u = __float_as_uint(f);
    unsigned int r = u + 0x7fffu + ((u >> 16) & 1u);
    return (ushort_t)(r >> 16);
}
__device__ __forceinline__ float b2f(ushort_t s){
    return __uint_as_float(((unsigned int)s) << 16);
}
__device__ __forceinline__ void split2(float x, ushort_t &hh, ushort_t &hl){
    hh = f32_to_bf16_rne(x);
    float r = x - b2f(hh);          // exact (Sterbenz)
    hl = f32_to_bf16_rne(r);
}
__device__ __forceinline__ f32x4_t mfma16(uint4 a, uint4 b, f32x4_t c){
    return __builtin_amdgcn_mfma_f32_16x16x32_bf16(
        __builtin_bit_cast(short8, a), __builtin_bit_cast(short8, b), c, 0, 0, 0);
}
__device__ __forceinline__ float sigm(float x){
    return __fdividef(1.f, 1.f + __expf(-x));
}
__device__ __forceinline__ float tanh_f(float x){
    return 1.f - __fdividef(2.f, 1.f + __expf(2.f * x));
}

// ---------------------------------------------------------------------------
// Fused prep kernel (UNCHANGED from the R2/R7 kernel that passed on HW).
// ---------------------------------------------------------------------------
__global__ void prep_kernel(
    const float* __restrict__ Whh_enc, const float* __restrict__ Whh_gru,
    const float* __restrict__ Wih_gru, const float* __restrict__ token_emb,
    const float* __restrict__ Wih_enc, const float* __restrict__ bih_enc,
    const float* __restrict__ bhh_enc, const float* __restrict__ index_tab,
    const float* __restrict__ bih_gru, const float* __restrict__ bhh_gru,
    const float* __restrict__ choice_tab,
    ushort_t* __restrict__ enc_h, ushort_t* __restrict__ enc_l,
    ushort_t* __restrict__ gru_h, ushort_t* __restrict__ gru_l,
    ushort_t* __restrict__ mid_h, ushort_t* __restrict__ mid_l,
    float* __restrict__ tok_proj, float* __restrict__ xproj)
{
    __shared__ __align__(16) float s_a[304];
    __shared__ __align__(16) float s_b[304];
    const int tid = threadIdx.x;
    const int bid = blockIdx.x;

    if (bid < 1792){
        const int idx = bid * 256 + tid;          // < 458752
        float v; ushort_t *ph, *pl; int fi;
        if (idx < 65536){
            fi = idx;
            const int m = fi & 7, lane = (fi >> 3) & 63, t2 = fi >> 9;
            const int nt = t2 & 15, kt = t2 >> 4;
            const int k = (kt << 5) + ((lane >> 4) << 3) + m;
            const int j = (nt << 4) + (lane & 15);
            v = Whh_enc[(j << 8) + k]; ph = enc_h; pl = enc_l;
        } else if (idx < 262144){
            fi = idx - 65536;
            const int m = fi & 7, lane = (fi >> 3) & 63, t2 = fi >> 9;
            const int nt = t2 % 48, kt = t2 / 48;
            const int k = (kt << 5) + ((lane >> 4) << 3) + m;
            const int j = (nt << 4) + (lane & 15);
            v = Whh_gru[(j << 8) + k]; ph = gru_h; pl = gru_l;
        } else {
            fi = idx - 262144;
            const int m = fi & 7, lane = (fi >> 3) & 63, t2 = fi >> 9;
            const int nt = t2 % 48, kt = t2 / 48;
            const int k = (kt << 5) + ((lane >> 4) << 3) + m;
            const int j = (nt << 4) + (lane & 15);
            v = Wih_gru[j * 856 + 300 + k]; ph = mid_h; pl = mid_l;
        }
        ushort_t hh, hl; split2(v, hh, hl);
        ph[fi] = hh; pl[fi] = hl;
    } else if (bid < 3328){
        const int b2 = bid - 1792;                // 0..1535
        const int co = b2 / 3, part = b2 - co * 3;  // co = c*16+o in 0..511
        const int c = co >> 4;
        const int g = part * 256 + tid;           // 0..767
        for (int i2 = tid; i2 < 300; i2 += 256){
            s_a[i2] = choice_tab[co * 300 + i2];
            s_b[i2] = index_tab[c * 300 + i2];
        }
        __syncthreads();
        float acc = bih_gru[g] + (g < 512 ? bhh_gru[g] : 0.f);
        const f32x4_t* wa = (const f32x4_t*)(Wih_gru + g * 856);        // cols 0..299
        const f32x4_t* wb = (const f32x4_t*)(Wih_gru + g * 856 + 556);  // cols 556..855
        const f32x4_t* xa = (const f32x4_t*)s_a;
        const f32x4_t* xb = (const f32x4_t*)s_b;
        #pragma unroll 5
        for (int e = 0; e < 75; ++e){
            f32x4_t a = xa[e], w0 = wa[e], b = xb[e], w1 = wb[e];
            acc += a[0]*w0[0] + a[1]*w0[1] + a[2]*w0[2] + a[3]*w0[3]
                 + b[0]*w1[0] + b[1]*w1[1] + b[2]*w1[2] + b[3]*w1[3];
        }
        xproj[co * 768 + g] = acc;
    } else {
        const int v0 = bid - 3328;                // token id 0..999
        for (int i2 = tid; i2 < 300; i2 += 256) s_a[i2] = token_emb[v0 * 300 + i2];
        __syncthreads();
        float acc = bih_enc[tid] + bhh_enc[tid];
        const f32x4_t* wa = (const f32x4_t*)(Wih_enc + tid * 300);
        const f32x4_t* xa = (const f32x4_t*)s_a;
        #pragma unroll 5
        for (int e = 0; e < 75; ++e){
            f32x4_t a = xa[e], b = wa[e];
            acc += a[0]*b[0] + a[1]*b[1] + a[2]*b[2] + a[3]*b[3];
        }
        tok_proj[(v0 << 8) + tid] = acc;
    }
}

// ---------------------------------------------------------------------------
// Encoder (UNCHANGED from R7-passing build). 128 blocks x 256 thr, 16 rows,
// register-resident split weights, tokproj prefetch.
// ---------------------------------------------------------------------------
__global__ __launch_bounds__(256, 1) void enc_kernel(
    const int* __restrict__ program, const int* __restrict__ plen,
    const float* __restrict__ h0, const float* __restrict__ tokproj,
    const ushort_t* __restrict__ enc_h, const ushort_t* __restrict__ enc_l,
    const ushort_t* __restrict__ mid_h, const ushort_t* __restrict__ mid_l,
    float* __restrict__ prog_proj)
{
    __shared__ __align__(16) ushort_t hbuf[2][2][16 * 256];
    __shared__ int prog_s[16 * 128];
    const int tid = threadIdx.x, bid = blockIdx.x;
    const int wave = tid >> 6, lane = tid & 63;
    const int r0 = bid << 4;

    for (int i = tid; i < 2048; i += 256) prog_s[i] = program[(r0 << 7) + i];

    const int rowbase = (lane >> 4) << 2;
    const int jbase = (wave << 6) + (lane & 15);
    int plen_r[4];
    #pragma unroll
    for (int i = 0; i < 4; ++i) plen_r[i] = plen[r0 + rowbase + i];

    const uint4* __restrict__ be_h = (const uint4*)enc_h;
    const uint4* __restrict__ be_l = (const uint4*)enc_l;
    uint4 bh_r[8][4], bl_r[8][4];
    #pragma unroll
    for (int kt = 0; kt < 8; ++kt)
    #pragma unroll
    for (int q = 0; q < 4; ++q){
        const int fo = (((kt << 4) + (wave << 2) + q) << 6) + lane;
        bh_r[kt][q] = be_h[fo];
        bl_r[kt][q] = be_l[fo];
    }

    float hreg[4][4];
    #pragma unroll
    for (int q = 0; q < 4; ++q)
    #pragma unroll
    for (int i = 0; i < 4; ++i){
        const int row = rowbase + i, j = jbase + (q << 4);
        float v = h0[((r0 + row) << 8) + j];
        hreg[q][i] = v;
        ushort_t hh, hl; split2(v, hh, hl);
        const int b0 = (((row << 9) + (j << 1)) ^ ((row & 7) << 4)) >> 1;
        hbuf[0][0][b0] = hh; hbuf[0][1][b0] = hl;
    }
    __syncthreads();

    const int arow = lane & 15;
    const int abase = (arow << 9) + ((lane >> 4) << 4);
    const int asw = (arow & 7) << 4;
    int cur = 0;

    // prefetch t=0 tokproj
    float nxt[4][4];
    {
        int tok[4];
        #pragma unroll
        for (int i = 0; i < 4; ++i) tok[i] = prog_s[((rowbase + i) << 7)];
        #pragma unroll
        for (int q = 0; q < 4; ++q)
        #pragma unroll
        for (int i = 0; i < 4; ++i)
            nxt[q][i] = tokproj[(tok[i] << 8) + jbase + (q << 4)];
    }

    for (int t = 0; t < 128; ++t){
        f32x4_t acc[4];
        #pragma unroll
        for (int q = 0; q < 4; ++q)
        #pragma unroll
        for (int i = 0; i < 4; ++i)
            acc[q][i] = nxt[q][i];

        if (t < 127){
            int tok[4];
            #pragma unroll
            for (int i = 0; i < 4; ++i) tok[i] = prog_s[((rowbase + i) << 7) + t + 1];
            #pragma unroll
            for (int q = 0; q < 4; ++q)
            #pragma unroll
            for (int i = 0; i < 4; ++i)
                nxt[q][i] = tokproj[(tok[i] << 8) + jbase + (q << 4)];
        }

        #pragma unroll
        for (int kt = 0; kt < 8; ++kt){
            const int b = ((abase + (kt << 6)) ^ asw) >> 1;
            const uint4 ah = *(const uint4*)&hbuf[cur][0][b];
            const uint4 al = *(const uint4*)&hbuf[cur][1][b];
            #pragma unroll
            for (int q = 0; q < 4; ++q){
                f32x4_t c = acc[q];
                c = mfma16(ah, bh_r[kt][q], c);
                c = mfma16(al, bh_r[kt][q], c);
                c = mfma16(ah, bl_r[kt][q], c);
                acc[q] = c;
            }
        }
        const int nb = cur ^ 1;
        #pragma unroll
        for (int q = 0; q < 4; ++q)
        #pragma unroll
        for (int i = 0; i < 4; ++i){
            const int row = rowbase + i, j = jbase + (q << 4);
            float v = (t < plen_r[i]) ? tanh_f(acc[q][i]) : hreg[q][i];
            hreg[q][i] = v;
            ushort_t hh, hl; split2(v, hh, hl);
            const int b0 = (((row << 9) + (j << 1)) ^ ((row & 7) << 4)) >> 1;
            hbuf[nb][0][b0] = hh; hbuf[nb][1][b0] = hl;
        }
        cur = nb;
        __syncthreads();
    }

    // prog_proj = prog_h @ Wmid^T (split-bf16 MFMA), one-time stream of mid tables
    uint4 ahr[8], alr[8];
    #pragma unroll
    for (int kt = 0; kt < 8; ++kt){
        const int b = ((abase + (kt << 6)) ^ asw) >> 1;
        ahr[kt] = *(const uint4*)&hbuf[cur][0][b];
        alr[kt] = *(const uint4*)&hbuf[cur][1][b];
    }
    const uint4* __restrict__ bm_h = (const uint4*)mid_h;
    const uint4* __restrict__ bm_l = (const uint4*)mid_l;
    f32x4_t pacc[12];
    #pragma unroll
    for (int u = 0; u < 12; ++u){ f32x4_t z = {0.f,0.f,0.f,0.f}; pacc[u] = z; }
    #pragma unroll
    for (int kt = 0; kt < 8; ++kt){
        #pragma unroll
        for (int u = 0; u < 12; ++u){
            const int nt = wave * 12 + u;
            const int fo = ((kt * 48 + nt) << 6) + lane;
            const uint4 bh = bm_h[fo], bl = bm_l[fo];
            f32x4_t c = pacc[u];
            c = mfma16(ahr[kt], bh, c);
            c = mfma16(alr[kt], bh, c);
            c = mfma16(ahr[kt], bl, c);
            pacc[u] = c;
        }
    }
    #pragma unroll
    for (int u = 0; u < 12; ++u){
        const int g = (wave * 12 + u) * 16 + (lane & 15);
        #pragma unroll
        for (int i = 0; i < 4; ++i)
            prog_proj[(r0 + rowbase + i) * 768 + g] = pacc[u][i];
    }
}

// ---------------------------------------------------------------------------
// Decoder v3 = v2 + prog_proj hoisted to registers (ppr, step-invariant).
// 64 blocks x 512 thr (8 waves), 32 rows/block; wave owns j-chunk(32) for all
// rows. Per-XCD L2 working set after hoist: weights 786KB + xproj 1.5MB +
// infW 512KB ~= 2.8MB < 4MB -> weight stream should now be L2-resident.
// ---------------------------------------------------------------------------
__global__ __launch_bounds__(512, 2) void dec_kernel(
    const int* __restrict__ trace, const int* __restrict__ choices,
    const float* __restrict__ h0, const float* __restrict__ prog_proj,
    const float* __restrict__ xproj,
    const ushort_t* __restrict__ gru_h, const ushort_t* __restrict__ gru_l,
    const float* __restrict__ bhh_gru, const float* __restrict__ infW,
    const float* __restrict__ infb, float* __restrict__ out)
{
    __shared__ __align__(16) ushort_t hbuf[2][32 * 256];   // hi/lo planes, 16KB each
    __shared__ int trace_s[32 * 64];
    __shared__ int choice_s[32 * 32];
    const int tid = threadIdx.x, bid = blockIdx.x;
    const int wave = tid >> 6, lane = tid & 63;
    const int r0 = bid << 5;

    for (int i = tid; i < 2048; i += 512) trace_s[i] = trace[(r0 << 6) + i];
    for (int i = tid; i < 1024; i += 512) choice_s[i] = choices[(r0 << 5) + i];

    // fill hbuf planes from h0 (32 rows x 256)
    #pragma unroll
    for (int e = 0; e < 16; ++e){
        const int i = (e << 9) + tid;
        const int row = i >> 8, j = i & 255;
        float v = h0[((r0 + row) << 8) + j];
        ushort_t hh, hl; split2(v, hh, hl);
        const int b0 = (((row << 9) + (j << 1)) ^ ((row & 7) << 4)) >> 1;
        hbuf[0][b0] = hh; hbuf[1][b0] = hl;
    }

    const int crow = (lane >> 4) << 2;             // C/D row base within 16-tile
    const int jcol = (wave << 5) + (lane & 15);    // this wave's j-chunk base col
    float bhhn[2];
    #pragma unroll
    for (int jt = 0; jt < 2; ++jt) bhhn[jt] = bhh_gru[512 + jcol + (jt << 4)];
    float hreg[2][2][4];
    #pragma unroll
    for (int rt = 0; rt < 2; ++rt)
    #pragma unroll
    for (int jt = 0; jt < 2; ++jt)
    #pragma unroll
    for (int rg = 0; rg < 4; ++rg)
        hreg[rt][jt][rg] = h0[((r0 + (rt << 4) + crow + rg) << 8) + jcol + (jt << 4)];

    // step-invariant prog_proj contribution, register-resident (48 VGPR)
    float ppr[3][2][2][4];
    #pragma unroll
    for (int rt = 0; rt < 2; ++rt)
    #pragma unroll
    for (int rg = 0; rg < 4; ++rg){
        const int lrow = (rt << 4) + crow + rg;
        const float* pb = prog_proj + (r0 + lrow) * 768;
        #pragma unroll
        for (int g = 0; g < 3; ++g)
        #pragma unroll
        for (int jt = 0; jt < 2; ++jt)
            ppr[g][rt][jt][rg] = pb[(g << 8) + jcol + (jt << 4)];
    }
    __syncthreads();

    const uint4* __restrict__ bg_h = (const uint4*)gru_h;
    const uint4* __restrict__ bg_l = (const uint4*)gru_l;
    const int arow = lane & 15;
    const int abase = (arow << 9) + ((lane >> 4) << 4);
    const int asw = (arow & 7) << 4;

    for (int t = 0; t < 63; ++t){
        f32x4_t acc[3][2][2];
        #pragma unroll
        for (int rt = 0; rt < 2; ++rt)
        #pragma unroll
        for (int jt = 0; jt < 2; ++jt){
            f32x4_t z4 = {0.f, 0.f, 0.f, 0.f};
            acc[0][rt][jt] = z4; acc[1][rt][jt] = z4;
            f32x4_t bn = {bhhn[jt], bhhn[jt], bhhn[jt], bhhn[jt]};
            acc[2][rt][jt] = bn;
        }

        float xv[3][2][2][4];
        #pragma unroll
        for (int half = 0; half < 2; ++half){
            if (half == 1){
                // x-side gathers (xproj only; prog_proj is in ppr): hidden under kt=4..7
                #pragma unroll
                for (int rt = 0; rt < 2; ++rt)
                #pragma unroll
                for (int rg = 0; rg < 4; ++rg){
                    const int lrow = (rt << 4) + crow + rg;
                    const int prev = trace_s[(lrow << 6) + t];
                    const int opt = choice_s[(lrow << 5) + prev];
                    const float* xb = xproj + ((prev << 4) + opt) * 768;
                    #pragma unroll
                    for (int g = 0; g < 3; ++g)
                    #pragma unroll
                    for (int jt = 0; jt < 2; ++jt){
                        const int jj = (g << 8) + jcol + (jt << 4);
                        xv[g][rt][jt][rg] = xb[jj] + ppr[g][rt][jt][rg];
                    }
                }
            }
            #pragma unroll
            for (int kt4 = 0; kt4 < 4; ++kt4){
                const int kt = (half << 2) + kt4;
                uint4 ah[2], al[2];
                #pragma unroll
                for (int rt = 0; rt < 2; ++rt){
                    const int b = (((rt << 13) + abase + (kt << 6)) ^ asw) >> 1;
                    ah[rt] = *(const uint4*)&hbuf[0][b];
                    al[rt] = *(const uint4*)&hbuf[1][b];
                }
                #pragma unroll
                for (int g = 0; g < 3; ++g)
                #pragma unroll
                for (int jt = 0; jt < 2; ++jt){
                    const int nt = (g << 4) + (wave << 1) + jt;
                    const int fo = ((kt * 48 + nt) << 6) + lane;
                    const uint4 bh = bg_h[fo], bl = bg_l[fo];
                    #pragma unroll
                    for (int rt = 0; rt < 2; ++rt){
                        f32x4_t c = acc[g][rt][jt];
                        c = mfma16(ah[rt], bh, c);
                        c = mfma16(al[rt], bh, c);
                        c = mfma16(ah[rt], bl, c);
                        acc[g][rt][jt] = c;
                    }
                }
            }
        }

        // gates into registers (no LDS writes yet — other waves still read h_old)
        ushort_t wh[2][2][4], wl[2][2][4];
        #pragma unroll
        for (int rt = 0; rt < 2; ++rt)
        #pragma unroll
        for (int jt = 0; jt < 2; ++jt)
        #pragma unroll
        for (int rg = 0; rg < 4; ++rg){
            const float rr = sigm(acc[0][rt][jt][rg] + xv[0][rt][jt][rg]);
            const float zz = sigm(acc[1][rt][jt][rg] + xv[1][rt][jt][rg]);
            const float nn = tanh_f(xv[2][rt][jt][rg] + rr * acc[2][rt][jt][rg]);
            const float hv = (1.f - zz) * nn + zz * hreg[rt][jt][rg];
            hreg[rt][jt][rg] = hv;
            split2(hv, wh[rt][jt][rg], wl[rt][jt][rg]);
        }
        __syncthreads();   // (1) all A-reads of h_old complete
        #pragma unroll
        for (int rt = 0; rt < 2; ++rt)
        #pragma unroll
        for (int jt = 0; jt < 2; ++jt)
        #pragma unroll
        for (int rg = 0; rg < 4; ++rg){
            const int row = (rt << 4) + crow + rg;
            const int j = jcol + (jt << 4);
            const int b0 = (((row << 9) + (j << 1)) ^ ((row & 7) << 4)) >> 1;
            hbuf[0][b0] = wh[rt][jt][rg];
            hbuf[1][b0] = wl[rt][jt][rg];
        }
        __syncthreads();   // (2) h_new published

        // fused head: thread=(row, ks); partials over k-slice 16; butterfly reduce
        {
            const int prow = tid >> 4, ks = tid & 15;
            const int ct = trace_s[(prow << 6) + t + 1];
            const int psw = (prow & 7) << 4;
            const int ba = (((prow << 9) + (ks << 5)) ^ psw) >> 1;
            const int bb = (((prow << 9) + (ks << 5) + 16) ^ psw) >> 1;
            union { uint4 v; ushort_t u[8]; } H0, H1, L0, L1;
            H0.v = *(const uint4*)&hbuf[0][ba];
            H1.v = *(const uint4*)&hbuf[0][bb];
            L0.v = *(const uint4*)&hbuf[1][ba];
            L1.v = *(const uint4*)&hbuf[1][bb];
            float hv16[16];
            #pragma unroll
            for (int n2 = 0; n2 < 8; ++n2){
                hv16[n2]     = b2f(H0.u[n2]) + b2f(L0.u[n2]);
                hv16[8 + n2] = b2f(H1.u[n2]) + b2f(L1.u[n2]);
            }
            const float* iwb = infW + ((size_t)ct << 12) + (ks << 4);
            float s[16];
            #pragma unroll
            for (int o = 0; o < 16; ++o){
                const f32x4_t* wp = (const f32x4_t*)(iwb + (o << 8));
                const f32x4_t w0 = wp[0], w1 = wp[1], w2 = wp[2], w3 = wp[3];
                s[o] =
                    hv16[0]*w0[0] + hv16[1]*w0[1] + hv16[2]*w0[2] + hv16[3]*w0[3]
                  + hv16[4]*w1[0] + hv16[5]*w1[1] + hv16[6]*w1[2] + hv16[7]*w1[3]
                  + hv16[8]*w2[0] + hv16[9]*w2[1] + hv16[10]*w2[2]+ hv16[11]*w2[3]
                  + hv16[12]*w3[0]+ hv16[13]*w3[1]+ hv16[14]*w3[2]+ hv16[15]*w3[3];
            }
            // tree-reduce across the 16 ks-lanes; lane keeps o == ks (static idx only)
            #pragma unroll
            for (int m = 1; m < 16; m <<= 1){
                const int keep_hi = ks & m;
                #pragma unroll
                for (int i = 0; i < 16 / (m * 2); ++i){
                    const float a = s[2*i], b = s[2*i + 1];
                    const float axx = __shfl_xor(a, m);
                    const float bxx = __shfl_xor(b, m);
                    s[i] = keep_hi ? (b + bxx) : (a + axx);
                }
            }
            out[(size_t)t * 32768 + ((size_t)(r0 + prow) << 4) + ks] =
                s[0] + infb[(ct << 4) + ks];
        }
    }
}

// ---------------------------------------------------------------------------
extern "C" void kernel_launch(void* const* d_in, const int* in_sizes, int n_in,
                              void* d_out, int out_size, void* d_ws, size_t ws_size,
                              hipStream_t stream)
{
    const int*   program   = (const int*)  d_in[0];
    const int*   plen      = (const int*)  d_in[1];
    const int*   trace     = (const int*)  d_in[2];
    // d_in[3] = trace_len: unused by the reference computation
    const int*   choices   = (const int*)  d_in[4];
    const float* h0_enc    = (const float*)d_in[5];
    const float* h0_dec    = (const float*)d_in[6];
    const float* token_emb = (const float*)d_in[7];
    const float* Wih_enc   = (const float*)d_in[8];
    const float* Whh_enc   = (const float*)d_in[9];
    const float* bih_enc   = (const float*)d_in[10];
    const float* bhh_enc   = (const float*)d_in[11];
    const float* choice_tab= (const float*)d_in[12];
    const float* index_tab = (const float*)d_in[13];
    const float* Wih_gru   = (const float*)d_in[14];
    const float* Whh_gru   = (const float*)d_in[15];
    const float* bih_gru   = (const float*)d_in[16];
    const float* bhh_gru   = (const float*)d_in[17];
    const float* infW      = (const float*)d_in[18];
    const float* infb      = (const float*)d_in[19];
    float* out = (float*)d_out;

    char* w = (char*)d_ws;                       // ~10.3 MB used
    ushort_t* enc_h = (ushort_t*)(w + 0);        // 131072 B
    ushort_t* enc_l = (ushort_t*)(w + 131072);
    ushort_t* gru_h = (ushort_t*)(w + 262144);   // 393216 B
    ushort_t* gru_l = (ushort_t*)(w + 655360);
    ushort_t* mid_h = (ushort_t*)(w + 1048576);
    ushort_t* mid_l = (ushort_t*)(w + 1441792);
    float* tok_proj = (float*)(w + 1835008);     // 1000*256 f32
    float* xproj    = (float*)(w + 2859008);     // 512*768 f32
    float* prog_proj= (float*)(w + 4431872);     // 2048*768 f32

    prep_kernel<<<4328, 256, 0, stream>>>(
        Whh_enc, Whh_gru, Wih_gru, token_emb, Wih_enc, bih_enc, bhh_enc,
        index_tab, bih_gru, bhh_gru, choice_tab,
        enc_h, enc_l, gru_h, gru_l, mid_h, mid_l,
        tok_proj, xproj);

    enc_kernel<<<128, 256, 0, stream>>>(
        program, plen, h0_enc, tok_proj, enc_h, enc_l, mid_h, mid_l, prog_proj);

    dec_kernel<<<64, 512, 0, stream>>>(
        trace, choices, h0_dec, prog_proj, xproj,
        gru_h, gru_l, bhh_gru, infW, infb, out);
}

// Round 9
// 3448.087 us; speedup vs baseline: 1.0077x; 1.0077x over previous
//
#include <hip/hip_runtime.h>

// GrammarInference: encoder tanh-RNN (128 steps) + GRU decoder (63 steps) + per-step head.
// R8 post-mortem: prog_proj hoist was rematerialized by the compiler (VGPR stayed 128,
// FETCH unchanged) and prog_proj was L2-hot anyway. Real bottleneck: 45.7us/step =
// ~96 weight-fragment loads x ~1000cyc fully SERIALIZED (MfmaUtil 2%, CU idle 95%).
// Dec v4: register double-buffered 6-group load pipeline -- issue group c+1's 16
// independent uint4 loads before consuming group c's 48 MFMAs; xv gathers moved to a
// post-MFMA phase (96 indep loads, one drain). Same math, bit-identical accumulation.
//
// B=2048 P=128 T=64 V=1000 NC=32 NO=16 E=300 H=256 GIN=856, out = [63,2048,16] f32.

typedef unsigned short ushort_t;
typedef short short8 __attribute__((ext_vector_type(8)));
typedef float f32x4_t __attribute__((ext_vector_type(4)));

__device__ __forceinline__ ushort_t f32_to_bf16_rne(float f){
    unsigned int u = __float_as_uint(f);
    unsigned int r = u + 0x7fffu + ((u >> 16) & 1u);
    return (ushort_t)(r >> 16);
}
__device__ __forceinline__ float b2f(ushort_t s){
    return __uint_as_float(((unsigned int)s) << 16);
}
__device__ __forceinline__ void split2(float x, ushort_t &hh, ushort_t &hl){
    hh = f32_to_bf16_rne(x);
    float r = x - b2f(hh);          // exact (Sterbenz)
    hl = f32_to_bf16_rne(r);
}
__device__ __forceinline__ f32x4_t mfma16(uint4 a, uint4 b, f32x4_t c){
    return __builtin_amdgcn_mfma_f32_16x16x32_bf16(
        __builtin_bit_cast(short8, a), __builtin_bit_cast(short8, b), c, 0, 0, 0);
}
__device__ __forceinline__ float sigm(float x){
    return __fdividef(1.f, 1.f + __expf(-x));
}
__device__ __forceinline__ float tanh_f(float x){
    return 1.f - __fdividef(2.f, 1.f + __expf(2.f * x));
}

// ---------------------------------------------------------------------------
// Fused prep kernel (UNCHANGED from the R2/R7/R8 kernel that passed on HW).
// ---------------------------------------------------------------------------
__global__ void prep_kernel(
    const float* __restrict__ Whh_enc, const float* __restrict__ Whh_gru,
    const float* __restrict__ Wih_gru, const float* __restrict__ token_emb,
    const float* __restrict__ Wih_enc, const float* __restrict__ bih_enc,
    const float* __restrict__ bhh_enc, const float* __restrict__ index_tab,
    const float* __restrict__ bih_gru, const float* __restrict__ bhh_gru,
    const float* __restrict__ choice_tab,
    ushort_t* __restrict__ enc_h, ushort_t* __restrict__ enc_l,
    ushort_t* __restrict__ gru_h, ushort_t* __restrict__ gru_l,
    ushort_t* __restrict__ mid_h, ushort_t* __restrict__ mid_l,
    float* __restrict__ tok_proj, float* __restrict__ xproj)
{
    __shared__ __align__(16) float s_a[304];
    __shared__ __align__(16) float s_b[304];
    const int tid = threadIdx.x;
    const int bid = blockIdx.x;

    if (bid < 1792){
        const int idx = bid * 256 + tid;          // < 458752
        float v; ushort_t *ph, *pl; int fi;
        if (idx < 65536){
            fi = idx;
            const int m = fi & 7, lane = (fi >> 3) & 63, t2 = fi >> 9;
            const int nt = t2 & 15, kt = t2 >> 4;
            const int k = (kt << 5) + ((lane >> 4) << 3) + m;
            const int j = (nt << 4) + (lane & 15);
            v = Whh_enc[(j << 8) + k]; ph = enc_h; pl = enc_l;
        } else if (idx < 262144){
            fi = idx - 65536;
            const int m = fi & 7, lane = (fi >> 3) & 63, t2 = fi >> 9;
            const int nt = t2 % 48, kt = t2 / 48;
            const int k = (kt << 5) + ((lane >> 4) << 3) + m;
            const int j = (nt << 4) + (lane & 15);
            v = Whh_gru[(j << 8) + k]; ph = gru_h; pl = gru_l;
        } else {
            fi = idx - 262144;
            const int m = fi & 7, lane = (fi >> 3) & 63, t2 = fi >> 9;
            const int nt = t2 % 48, kt = t2 / 48;
            const int k = (kt << 5) + ((lane >> 4) << 3) + m;
            const int j = (nt << 4) + (lane & 15);
            v = Wih_gru[j * 856 + 300 + k]; ph = mid_h; pl = mid_l;
        }
        ushort_t hh, hl; split2(v, hh, hl);
        ph[fi] = hh; pl[fi] = hl;
    } else if (bid < 3328){
        const int b2 = bid - 1792;                // 0..1535
        const int co = b2 / 3, part = b2 - co * 3;  // co = c*16+o in 0..511
        const int c = co >> 4;
        const int g = part * 256 + tid;           // 0..767
        for (int i2 = tid; i2 < 300; i2 += 256){
            s_a[i2] = choice_tab[co * 300 + i2];
            s_b[i2] = index_tab[c * 300 + i2];
        }
        __syncthreads();
        float acc = bih_gru[g] + (g < 512 ? bhh_gru[g] : 0.f);
        const f32x4_t* wa = (const f32x4_t*)(Wih_gru + g * 856);        // cols 0..299
        const f32x4_t* wb = (const f32x4_t*)(Wih_gru + g * 856 + 556);  // cols 556..855
        const f32x4_t* xa = (const f32x4_t*)s_a;
        const f32x4_t* xb = (const f32x4_t*)s_b;
        #pragma unroll 5
        for (int e = 0; e < 75; ++e){
            f32x4_t a = xa[e], w0 = wa[e], b = xb[e], w1 = wb[e];
            acc += a[0]*w0[0] + a[1]*w0[1] + a[2]*w0[2] + a[3]*w0[3]
                 + b[0]*w1[0] + b[1]*w1[1] + b[2]*w1[2] + b[3]*w1[3];
        }
        xproj[co * 768 + g] = acc;
    } else {
        const int v0 = bid - 3328;                // token id 0..999
        for (int i2 = tid; i2 < 300; i2 += 256) s_a[i2] = token_emb[v0 * 300 + i2];
        __syncthreads();
        float acc = bih_enc[tid] + bhh_enc[tid];
        const f32x4_t* wa = (const f32x4_t*)(Wih_enc + tid * 300);
        const f32x4_t* xa = (const f32x4_t*)s_a;
        #pragma unroll 5
        for (int e = 0; e < 75; ++e){
            f32x4_t a = xa[e], b = wa[e];
            acc += a[0]*b[0] + a[1]*b[1] + a[2]*b[2] + a[3]*b[3];
        }
        tok_proj[(v0 << 8) + tid] = acc;
    }
}

// ---------------------------------------------------------------------------
// Encoder (UNCHANGED from R7/R8-passing build). 128 blocks x 256 thr, 16 rows,
// register-resident split weights, tokproj prefetch.
// ---------------------------------------------------------------------------
__global__ __launch_bounds__(256, 1) void enc_kernel(
    const int* __restrict__ program, const int* __restrict__ plen,
    const float* __restrict__ h0, const float* __restrict__ tokproj,
    const ushort_t* __restrict__ enc_h, const ushort_t* __restrict__ enc_l,
    const ushort_t* __restrict__ mid_h, const ushort_t* __restrict__ mid_l,
    float* __restrict__ prog_proj)
{
    __shared__ __align__(16) ushort_t hbuf[2][2][16 * 256];
    __shared__ int prog_s[16 * 128];
    const int tid = threadIdx.x, bid = blockIdx.x;
    const int wave = tid >> 6, lane = tid & 63;
    const int r0 = bid << 4;

    for (int i = tid; i < 2048; i += 256) prog_s[i] = program[(r0 << 7) + i];

    const int rowbase = (lane >> 4) << 2;
    const int jbase = (wave << 6) + (lane & 15);
    int plen_r[4];
    #pragma unroll
    for (int i = 0; i < 4; ++i) plen_r[i] = plen[r0 + rowbase + i];

    const uint4* __restrict__ be_h = (const uint4*)enc_h;
    const uint4* __restrict__ be_l = (const uint4*)enc_l;
    uint4 bh_r[8][4], bl_r[8][4];
    #pragma unroll
    for (int kt = 0; kt < 8; ++kt)
    #pragma unroll
    for (int q = 0; q < 4; ++q){
        const int fo = (((kt << 4) + (wave << 2) + q) << 6) + lane;
        bh_r[kt][q] = be_h[fo];
        bl_r[kt][q] = be_l[fo];
    }

    float hreg[4][4];
    #pragma unroll
    for (int q = 0; q < 4; ++q)
    #pragma unroll
    for (int i = 0; i < 4; ++i){
        const int row = rowbase + i, j = jbase + (q << 4);
        float v = h0[((r0 + row) << 8) + j];
        hreg[q][i] = v;
        ushort_t hh, hl; split2(v, hh, hl);
        const int b0 = (((row << 9) + (j << 1)) ^ ((row & 7) << 4)) >> 1;
        hbuf[0][0][b0] = hh; hbuf[0][1][b0] = hl;
    }
    __syncthreads();

    const int arow = lane & 15;
    const int abase = (arow << 9) + ((lane >> 4) << 4);
    const int asw = (arow & 7) << 4;
    int cur = 0;

    // prefetch t=0 tokproj
    float nxt[4][4];
    {
        int tok[4];
        #pragma unroll
        for (int i = 0; i < 4; ++i) tok[i] = prog_s[((rowbase + i) << 7)];
        #pragma unroll
        for (int q = 0; q < 4; ++q)
        #pragma unroll
        for (int i = 0; i < 4; ++i)
            nxt[q][i] = tokproj[(tok[i] << 8) + jbase + (q << 4)];
    }

    for (int t = 0; t < 128; ++t){
        f32x4_t acc[4];
        #pragma unroll
        for (int q = 0; q < 4; ++q)
        #pragma unroll
        for (int i = 0; i < 4; ++i)
            acc[q][i] = nxt[q][i];

        if (t < 127){
            int tok[4];
            #pragma unroll
            for (int i = 0; i < 4; ++i) tok[i] = prog_s[((rowbase + i) << 7) + t + 1];
            #pragma unroll
            for (int q = 0; q < 4; ++q)
            #pragma unroll
            for (int i = 0; i < 4; ++i)
                nxt[q][i] = tokproj[(tok[i] << 8) + jbase + (q << 4)];
        }

        #pragma unroll
        for (int kt = 0; kt < 8; ++kt){
            const int b = ((abase + (kt << 6)) ^ asw) >> 1;
            const uint4 ah = *(const uint4*)&hbuf[cur][0][b];
            const uint4 al = *(const uint4*)&hbuf[cur][1][b];
            #pragma unroll
            for (int q = 0; q < 4; ++q){
                f32x4_t c = acc[q];
                c = mfma16(ah, bh_r[kt][q], c);
                c = mfma16(al, bh_r[kt][q], c);
                c = mfma16(ah, bl_r[kt][q], c);
                acc[q] = c;
            }
        }
        const int nb = cur ^ 1;
        #pragma unroll
        for (int q = 0; q < 4; ++q)
        #pragma unroll
        for (int i = 0; i < 4; ++i){
            const int row = rowbase + i, j = jbase + (q << 4);
            float v = (t < plen_r[i]) ? tanh_f(acc[q][i]) : hreg[q][i];
            hreg[q][i] = v;
            ushort_t hh, hl; split2(v, hh, hl);
            const int b0 = (((row << 9) + (j << 1)) ^ ((row & 7) << 4)) >> 1;
            hbuf[nb][0][b0] = hh; hbuf[nb][1][b0] = hl;
        }
        cur = nb;
        __syncthreads();
    }

    // prog_proj = prog_h @ Wmid^T (split-bf16 MFMA), one-time stream of mid tables
    uint4 ahr[8], alr[8];
    #pragma unroll
    for (int kt = 0; kt < 8; ++kt){
        const int b = ((abase + (kt << 6)) ^ asw) >> 1;
        ahr[kt] = *(const uint4*)&hbuf[cur][0][b];
        alr[kt] = *(const uint4*)&hbuf[cur][1][b];
    }
    const uint4* __restrict__ bm_h = (const uint4*)mid_h;
    const uint4* __restrict__ bm_l = (const uint4*)mid_l;
    f32x4_t pacc[12];
    #pragma unroll
    for (int u = 0; u < 12; ++u){ f32x4_t z = {0.f,0.f,0.f,0.f}; pacc[u] = z; }
    #pragma unroll
    for (int kt = 0; kt < 8; ++kt){
        #pragma unroll
        for (int u = 0; u < 12; ++u){
            const int nt = wave * 12 + u;
            const int fo = ((kt * 48 + nt) << 6) + lane;
            const uint4 bh = bm_h[fo], bl = bm_l[fo];
            f32x4_t c = pacc[u];
            c = mfma16(ahr[kt], bh, c);
            c = mfma16(alr[kt], bh, c);
            c = mfma16(ahr[kt], bl, c);
            pacc[u] = c;
        }
    }
    #pragma unroll
    for (int u = 0; u < 12; ++u){
        const int g = (wave * 12 + u) * 16 + (lane & 15);
        #pragma unroll
        for (int i = 0; i < 4; ++i)
            prog_proj[(r0 + rowbase + i) * 768 + g] = pacc[u][i];
    }
}

// ---------------------------------------------------------------------------
// Decoder v4: 64 blocks x 512 thr, 32 rows/block, wave owns j-chunk(32).
// NEW: register double-buffered B-fragment pipeline. Groups = (half,gate):
// 16 uint4 (64 VGPR) each; group c+1's 16 independent loads issue BEFORE
// group c's 48 MFMAs consume -- ~16 loads always in flight instead of ~1.
// xv gathers moved to a post-MFMA phase (96 indep loads, single drain) to cap
// peak live VGPRs (~215 < 256 @ 2 waves/SIMD). Accumulation order per acc[g]
// stays ascending-kt -> bit-identical to R7/R8 output.
// ---------------------------------------------------------------------------
__global__ __launch_bounds__(512, 2) void dec_kernel(
    const int* __restrict__ trace, const int* __restrict__ choices,
    const float* __restrict__ h0, const float* __restrict__ prog_proj,
    const float* __restrict__ xproj,
    const ushort_t* __restrict__ gru_h, const ushort_t* __restrict__ gru_l,
    const float* __restrict__ bhh_gru, const float* __restrict__ infW,
    const float* __restrict__ infb, float* __restrict__ out)
{
    __shared__ __align__(16) ushort_t hbuf[2][32 * 256];   // hi/lo planes, 16KB each
    __shared__ int trace_s[32 * 64];
    __shared__ int choice_s[32 * 32];
    const int tid = threadIdx.x, bid = blockIdx.x;
    const int wave = tid >> 6, lane = tid & 63;
    const int r0 = bid << 5;

    for (int i = tid; i < 2048; i += 512) trace_s[i] = trace[(r0 << 6) + i];
    for (int i = tid; i < 1024; i += 512) choice_s[i] = choices[(r0 << 5) + i];

    // fill hbuf planes from h0 (32 rows x 256)
    #pragma unroll
    for (int e = 0; e < 16; ++e){
        const int i = (e << 9) + tid;
        const int row = i >> 8, j = i & 255;
        float v = h0[((r0 + row) << 8) + j];
        ushort_t hh, hl; split2(v, hh, hl);
        const int b0 = (((row << 9) + (j << 1)) ^ ((row & 7) << 4)) >> 1;
        hbuf[0][b0] = hh; hbuf[1][b0] = hl;
    }

    const int crow = (lane >> 4) << 2;             // C/D row base within 16-tile
    const int jcol = (wave << 5) + (lane & 15);    // this wave's j-chunk base col
    float bhhn[2];
    #pragma unroll
    for (int jt = 0; jt < 2; ++jt) bhhn[jt] = bhh_gru[512 + jcol + (jt << 4)];
    float hreg[2][2][4];
    #pragma unroll
    for (int rt = 0; rt < 2; ++rt)
    #pragma unroll
    for (int jt = 0; jt < 2; ++jt)
    #pragma unroll
    for (int rg = 0; rg < 4; ++rg)
        hreg[rt][jt][rg] = h0[((r0 + (rt << 4) + crow + rg) << 8) + jcol + (jt << 4)];
    __syncthreads();

    const uint4* __restrict__ bg_h = (const uint4*)gru_h;
    const uint4* __restrict__ bg_l = (const uint4*)gru_l;
    const int arow = lane & 15;
    const int abase = (arow << 9) + ((lane >> 4) << 4);
    const int asw = (arow & 7) << 4;

    for (int t = 0; t < 63; ++t){
        f32x4_t acc[3][2][2];
        #pragma unroll
        for (int rt = 0; rt < 2; ++rt)
        #pragma unroll
        for (int jt = 0; jt < 2; ++jt){
            f32x4_t z4 = {0.f, 0.f, 0.f, 0.f};
            acc[0][rt][jt] = z4; acc[1][rt][jt] = z4;
            f32x4_t bn = {bhhn[jt], bhhn[jt], bhhn[jt], bhhn[jt]};
            acc[2][rt][jt] = bn;
        }

        // ---- B-fragment pipeline: 6 groups (half,g), 2-deep register dbuf ----
        uint4 BH[2][8], BL[2][8];
        // preload group 0 (half=0, g=0)
        #pragma unroll
        for (int kt4 = 0; kt4 < 4; ++kt4)
        #pragma unroll
        for (int jt = 0; jt < 2; ++jt){
            const int fo = ((kt4 * 48 + (wave << 1) + jt) << 6) + lane;
            BH[0][(kt4 << 1) + jt] = bg_h[fo];
            BL[0][(kt4 << 1) + jt] = bg_l[fo];
        }
        #pragma unroll
        for (int c = 0; c < 6; ++c){
            const int half = c / 3, g = c - half * 3;
            if (c < 5){
                const int h2 = (c + 1) / 3, g2 = (c + 1) - h2 * 3;
                #pragma unroll
                for (int kt4 = 0; kt4 < 4; ++kt4)
                #pragma unroll
                for (int jt = 0; jt < 2; ++jt){
                    const int kt = (h2 << 2) + kt4;
                    const int nt = (g2 << 4) + (wave << 1) + jt;
                    const int fo = ((kt * 48 + nt) << 6) + lane;
                    BH[(c + 1) & 1][(kt4 << 1) + jt] = bg_h[fo];
                    BL[(c + 1) & 1][(kt4 << 1) + jt] = bg_l[fo];
                }
            }
            // consume group c (ascending kt within each g -> same accum order)
            #pragma unroll
            for (int kt4 = 0; kt4 < 4; ++kt4){
                const int kt = (half << 2) + kt4;
                uint4 ah[2], al[2];
                #pragma unroll
                for (int rt = 0; rt < 2; ++rt){
                    const int b = (((rt << 13) + abase + (kt << 6)) ^ asw) >> 1;
                    ah[rt] = *(const uint4*)&hbuf[0][b];
                    al[rt] = *(const uint4*)&hbuf[1][b];
                }
                #pragma unroll
                for (int jt = 0; jt < 2; ++jt){
                    const uint4 bh = BH[c & 1][(kt4 << 1) + jt];
                    const uint4 bl = BL[c & 1][(kt4 << 1) + jt];
                    #pragma unroll
                    for (int rt = 0; rt < 2; ++rt){
                        f32x4_t cc = acc[g][rt][jt];
                        cc = mfma16(ah[rt], bh, cc);
                        cc = mfma16(al[rt], bh, cc);
                        cc = mfma16(ah[rt], bl, cc);
                        acc[g][rt][jt] = cc;
                    }
                }
            }
        }

        // ---- xv phase (after MFMAs; 96 independent loads, one drain) ----
        float xv[3][2][2][4];
        #pragma unroll
        for (int rt = 0; rt < 2; ++rt)
        #pragma unroll
        for (int rg = 0; rg < 4; ++rg){
            const int lrow = (rt << 4) + crow + rg;
            const int prev = trace_s[(lrow << 6) + t];
            const int opt = choice_s[(lrow << 5) + prev];
            const float* xb = xproj + ((prev << 4) + opt) * 768;
            const float* pb = prog_proj + (r0 + lrow) * 768;
            #pragma unroll
            for (int g = 0; g < 3; ++g)
            #pragma unroll
            for (int jt = 0; jt < 2; ++jt){
                const int jj = (g << 8) + jcol + (jt << 4);
                xv[g][rt][jt][rg] = xb[jj] + pb[jj];
            }
        }

        // gates into registers (no LDS writes yet — other waves still read h_old)
        ushort_t wh[2][2][4], wl[2][2][4];
        #pragma unroll
        for (int rt = 0; rt < 2; ++rt)
        #pragma unroll
        for (int jt = 0; jt < 2; ++jt)
        #pragma unroll
        for (int rg = 0; rg < 4; ++rg){
            const float rr = sigm(acc[0][rt][jt][rg] + xv[0][rt][jt][rg]);
            const float zz = sigm(acc[1][rt][jt][rg] + xv[1][rt][jt][rg]);
            const float nn = tanh_f(xv[2][rt][jt][rg] + rr * acc[2][rt][jt][rg]);
            const float hv = (1.f - zz) * nn + zz * hreg[rt][jt][rg];
            hreg[rt][jt][rg] = hv;
            split2(hv, wh[rt][jt][rg], wl[rt][jt][rg]);
        }
        __syncthreads();   // (1) all A-reads of h_old complete
        #pragma unroll
        for (int rt = 0; rt < 2; ++rt)
        #pragma unroll
        for (int jt = 0; jt < 2; ++jt)
        #pragma unroll
        for (int rg = 0; rg < 4; ++rg){
            const int row = (rt << 4) + crow + rg;
            const int j = jcol + (jt << 4);
            const int b0 = (((row << 9) + (j << 1)) ^ ((row & 7) << 4)) >> 1;
            hbuf[0][b0] = wh[rt][jt][rg];
            hbuf[1][b0] = wl[rt][jt][rg];
        }
        __syncthreads();   // (2) h_new published

        // fused head: thread=(row, ks); partials over k-slice 16; butterfly reduce
        {
            const int prow = tid >> 4, ks = tid & 15;
            const int ct = trace_s[(prow << 6) + t + 1];
            const int psw = (prow & 7) << 4;
            const int ba = (((prow << 9) + (ks << 5)) ^ psw) >> 1;
            const int bb = (((prow << 9) + (ks << 5) + 16) ^ psw) >> 1;
            union { uint4 v; ushort_t u[8]; } H0, H1, L0, L1;
            H0.v = *(const uint4*)&hbuf[0][ba];
            H1.v = *(const uint4*)&hbuf[0][bb];
            L0.v = *(const uint4*)&hbuf[1][ba];
            L1.v = *(const uint4*)&hbuf[1][bb];
            float hv16[16];
            #pragma unroll
            for (int n2 = 0; n2 < 8; ++n2){
                hv16[n2]     = b2f(H0.u[n2]) + b2f(L0.u[n2]);
                hv16[8 + n2] = b2f(H1.u[n2]) + b2f(L1.u[n2]);
            }
            const float* iwb = infW + ((size_t)ct << 12) + (ks << 4);
            float s[16];
            #pragma unroll
            for (int o = 0; o < 16; ++o){
                const f32x4_t* wp = (const f32x4_t*)(iwb + (o << 8));
                const f32x4_t w0 = wp[0], w1 = wp[1], w2 = wp[2], w3 = wp[3];
                s[o] =
                    hv16[0]*w0[0] + hv16[1]*w0[1] + hv16[2]*w0[2] + hv16[3]*w0[3]
                  + hv16[4]*w1[0] + hv16[5]*w1[1] + hv16[6]*w1[2] + hv16[7]*w1[3]
                  + hv16[8]*w2[0] + hv16[9]*w2[1] + hv16[10]*w2[2]+ hv16[11]*w2[3]
                  + hv16[12]*w3[0]+ hv16[13]*w3[1]+ hv16[14]*w3[2]+ hv16[15]*w3[3];
            }
            // tree-reduce across the 16 ks-lanes; lane keeps o == ks (static idx only)
            #pragma unroll
            for (int m = 1; m < 16; m <<= 1){
                const int keep_hi = ks & m;
                #pragma unroll
                for (int i = 0; i < 16 / (m * 2); ++i){
                    const float a = s[2*i], b = s[2*i + 1];
                    const float axx = __shfl_xor(a, m);
                    const float bxx = __shfl_xor(b, m);
                    s[i] = keep_hi ? (b + bxx) : (a + axx);
                }
            }
            out[(size_t)t * 32768 + ((size_t)(r0 + prow) << 4) + ks] =
                s[0] + infb[(ct << 4) + ks];
        }
    }
}

// ---------------------------------------------------------------------------
extern "C" void kernel_launch(void* const* d_in, const int* in_sizes, int n_in,
                              void* d_out, int out_size, void* d_ws, size_t ws_size,
                              hipStream_t stream)
{
    const int*   program   = (const int*)  d_in[0];
    const int*   plen      = (const int*)  d_in[1];
    const int*   trace     = (const int*)  d_in[2];
    // d_in[3] = trace_len: unused by the reference computation
    const int*   choices   = (const int*)  d_in[4];
    const float* h0_enc    = (const float*)d_in[5];
    const float* h0_dec    = (const float*)d_in[6];
    const float* token_emb = (const float*)d_in[7];
    const float* Wih_enc   = (const float*)d_in[8];
    const float* Whh_enc   = (const float*)d_in[9];
    const float* bih_enc   = (const float*)d_in[10];
    const float* bhh_enc   = (const float*)d_in[11];
    const float* choice_tab= (const float*)d_in[12];
    const float* index_tab = (const float*)d_in[13];
    const float* Wih_gru   = (const float*)d_in[14];
    const float* Whh_gru   = (const float*)d_in[15];
    const float* bih_gru   = (const float*)d_in[16];
    const float* bhh_gru   = (const float*)d_in[17];
    const float* infW      = (const float*)d_in[18];
    const float* infb      = (const float*)d_in[19];
    float* out = (float*)d_out;

    char* w = (char*)d_ws;                       // ~10.3 MB used
    ushort_t* enc_h = (ushort_t*)(w + 0);        // 131072 B
    ushort_t* enc_l = (ushort_t*)(w + 131072);
    ushort_t* gru_h = (ushort_t*)(w + 262144);   // 393216 B
    ushort_t* gru_l = (ushort_t*)(w + 655360);
    ushort_t* mid_h = (ushort_t*)(w + 1048576);
    ushort_t* mid_l = (ushort_t*)(w + 1441792);
    float* tok_proj = (float*)(w + 1835008);     // 1000*256 f32
    float* xproj    = (float*)(w + 2859008);     // 512*768 f32
    float* prog_proj= (float*)(w + 4431872);     // 2048*768 f32

    prep_kernel<<<4328, 256, 0, stream>>>(
        Whh_enc, Whh_gru, Wih_gru, token_emb, Wih_enc, bih_enc, bhh_enc,
        index_tab, bih_gru, bhh_gru, choice_tab,
        enc_h, enc_l, gru_h, gru_l, mid_h, mid_l,
        tok_proj, xproj);

    enc_kernel<<<128, 256, 0, stream>>>(
        program, plen, h0_enc, tok_proj, enc_h, enc_l, mid_h, mid_l, prog_proj);

    dec_kernel<<<64, 512, 0, stream>>>(
        trace, choices, h0_dec, prog_proj, xproj,
        gru_h, gru_l, bhh_gru, infW, infb, out);
}